// Round 2
// baseline (186.883 us; speedup 1.0000x reference)
//
#include <hip/hip_runtime.h>
#include <stdint.h>

// ---- problem constants (PointRCNN RPN, KITTI Car) ----
#define BN 4
#define NPTS 16384
#define REGC 76
#define PRE 2250
#define PRE_PAD 2304          // 18*128, padded stride
#define POST 128
#define NBINS 4096            // 12-bit histogram on flipped float key
#define SORTN 4096            // bitonic sort capacity for selected elements
#define ECAP 4096             // max suppression edges per image
#define NMS_T 0.8f
#define TI 18                 // ceil(PRE/128)
#define NTRI 171              // TI*(TI+1)/2 upper-triangle tiles per image
#define SZB (BN * PRE_PAD)    // per-array stride for BEV SoA

// Order-preserving float->uint flip: ascending uint == ascending float.
__device__ __forceinline__ uint32_t flip_f32(float f) {
  uint32_t u = __float_as_uint(f);
  return (u & 0x80000000u) ? ~u : (u | 0x80000000u);
}
__device__ __forceinline__ float unflip_f32(uint32_t k) {
  uint32_t u = (k & 0x80000000u) ? (k & 0x7FFFFFFFu) : ~k;
  return __uint_as_float(u);
}

// Kernel 1: per image, select top-PRE scores (exact, stable) and sort them.
// v2: wave-chunked bitonic — each of 8 waves owns a 512-elem chunk; all
// stages with j<=256 are wave-local (lockstep + in-order DS + volatile =>
// no __syncthreads). Only 6 cross-chunk stages (j>=512) use barriers.
// Suffix-sum likewise segmented per wave. Barrier count ~90 -> ~15.
__global__ __launch_bounds__(512) void k_select_sort(
    const float* __restrict__ scores, int* __restrict__ ws_idx,
    float* __restrict__ ws_score, int* __restrict__ edge_cnt) {
  __shared__ uint32_t hist[NBINS];                 // 16 KB
  __shared__ unsigned long long sel[SORTN];        // 32 KB
  __shared__ uint32_t tails[8];
  __shared__ int s_bt, s_cnt;
  const int img = blockIdx.x;
  const int tid = threadIdx.x;
  const int wave = tid >> 6, lane = tid & 63;
  const float* sc = scores + img * NPTS;

  for (int i = tid; i < NBINS; i += 512) hist[i] = 0u;
  for (int i = tid; i < SORTN; i += 512) sel[i] = ~0ULL;  // pad sorts last
  if (tid == 0) { s_cnt = 0; edge_cnt[img] = 0; }
  __syncthreads();

  for (int n = tid; n < NPTS; n += 512)
    atomicAdd(&hist[flip_f32(sc[n]) >> 20], 1u);
  __syncthreads();

  // wave-local inclusive suffix-sum within each 512-bin segment
  {
    volatile uint32_t* vh = hist;
    const int b0 = wave * 512;
    for (int off = 1; off < 512; off <<= 1) {
      uint32_t nv[8];
#pragma unroll
      for (int r = 0; r < 8; ++r) {
        int t = lane + r * 64;
        uint32_t x = vh[b0 + t];
        if (t + off < 512) x += vh[b0 + t + off];
        nv[r] = x;
      }
#pragma unroll
      for (int r = 0; r < 8; ++r) vh[b0 + lane + r * 64] = nv[r];
    }
  }
  __syncthreads();
  if (tid < 8) {  // tails[w] = total of segments strictly right of w
    uint32_t t = 0;
    for (int w = tid + 1; w < 8; ++w) t += hist[w * 512];
    tails[tid] = t;
  }
  __syncthreads();
  // bt = unique bin with suffix(bt) >= PRE > suffix(bt+1)
#pragma unroll
  for (int r = 0; r < 8; ++r) {
    int b = tid + r * 512;
    uint32_t s = hist[b] + tails[b >> 9];
    uint32_t sn = (b + 1 < NBINS) ? hist[b + 1] + tails[(b + 1) >> 9] : 0u;
    if (s >= (uint32_t)PRE && sn < (uint32_t)PRE) s_bt = b;
  }
  __syncthreads();
  const int bt = s_bt;

  // compact all elements with bin >= bt (superset of exact top-PRE)
  for (int n = tid; n < NPTS; n += 512) {
    uint32_t key = flip_f32(sc[n]);
    if ((int)(key >> 20) >= bt) {
      int p = atomicAdd(&s_cnt, 1);
      if (p < SORTN)
        sel[p] = ((unsigned long long)(~key) << 32) | (uint32_t)n;
    }
  }
  __syncthreads();

  // ---- bitonic ascending sort of SORTN u64, wave-chunked ----
  volatile unsigned long long* vs = sel;
  const int base = wave * 512;
  // Phase A: k = 2..512 (all j <= 256 stay inside the wave's chunk)
  for (int k = 2; k <= 512; k <<= 1) {
    for (int j = k >> 1; j > 0; j >>= 1) {
#pragma unroll
      for (int r = 0; r < 4; ++r) {
        int t = lane + r * 64;  // pair id within chunk, [0,256)
        int i = ((t & ~(j - 1)) << 1) | (t & (j - 1));
        int gi = base + i, gl = base + (i | j);
        unsigned long long a = vs[gi], b = vs[gl];
        if ((a > b) == ((gi & k) == 0)) { vs[gi] = b; vs[gl] = a; }
      }
    }
  }
  __syncthreads();
  // Phase B: k = 1024..4096; j >= 512 cross-chunk (barriered), j <= 256 local
  for (int k = 1024; k <= 4096; k <<= 1) {
    for (int j = k >> 1; j >= 512; j >>= 1) {
      for (int t = tid; t < 2048; t += 512) {
        int i = ((t & ~(j - 1)) << 1) | (t & (j - 1));
        int l = i | j;
        unsigned long long a = sel[i], b = sel[l];
        if ((a > b) == ((i & k) == 0)) { sel[i] = b; sel[l] = a; }
      }
      __syncthreads();
    }
    for (int j = 256; j > 0; j >>= 1) {
#pragma unroll
      for (int r = 0; r < 4; ++r) {
        int t = lane + r * 64;
        int i = ((t & ~(j - 1)) << 1) | (t & (j - 1));
        int gi = base + i, gl = base + (i | j);
        unsigned long long a = vs[gi], b = vs[gl];
        if ((a > b) == ((gi & k) == 0)) { vs[gi] = b; vs[gl] = a; }
      }
    }
    __syncthreads();
  }

  for (int r = tid; r < PRE; r += 512) {
    unsigned long long v = sel[r];
    ws_idx[img * PRE_PAD + r] = (int)(uint32_t)v;
    ws_score[img * PRE_PAD + r] = unflip_f32(~(uint32_t)(v >> 32));
  }
}

// Kernel 2: decode boxes for the BN*PRE selected rows; also emit BEV SoA.
__global__ __launch_bounds__(256) void k_decode(
    const float* __restrict__ reg, const float* __restrict__ xyz,
    const float* __restrict__ anchor, const int* __restrict__ ws_idx,
    float* __restrict__ ws_pr, float* __restrict__ bev) {
  int t = blockIdx.x * blockDim.x + threadIdx.x;
  if (t >= BN * PRE) return;
  int img = t / PRE;
  int r = t - img * PRE;
  int idx = ws_idx[img * PRE_PAD + r];

  const float* rr = reg + (size_t)(img * NPTS + idx) * REGC;
  float v[REGC];
  const float4* r4 = reinterpret_cast<const float4*>(rr);
#pragma unroll
  for (int q = 0; q < REGC / 4; ++q) {
    float4 f = r4[q];
    v[4 * q + 0] = f.x; v[4 * q + 1] = f.y;
    v[4 * q + 2] = f.z; v[4 * q + 3] = f.w;
  }

  // first-occurrence argmax (strict >) matches jnp.argmax
  int xb = 0; float xm = v[0];
#pragma unroll
  for (int c = 1; c < 12; ++c) if (v[c] > xm) { xm = v[c]; xb = c; }
  int zb = 0; float zm = v[12];
#pragma unroll
  for (int c = 1; c < 12; ++c) if (v[12 + c] > zm) { zm = v[12 + c]; zb = c; }
  float xres = v[24];
#pragma unroll
  for (int c = 1; c < 12; ++c) if (xb == c) xres = v[24 + c];
  float zres = v[36];
#pragma unroll
  for (int c = 1; c < 12; ++c) if (zb == c) zres = v[36 + c];

  float posx = xb * 0.5f + 0.25f - 3.0f + xres * 0.5f;
  float posz = zb * 0.5f + 0.25f - 3.0f + zres * 0.5f;

  const float* xp = xyz + (size_t)(img * NPTS + idx) * 3;
  float X = posx + xp[0];
  float Y = xp[1] + v[48];
  float Z = posz + xp[2];

  int ryb = 0; float rym = v[49];
#pragma unroll
  for (int c = 1; c < 12; ++c) if (v[49 + c] > rym) { rym = v[49 + c]; ryb = c; }
  float ryres = v[61];
#pragma unroll
  for (int c = 1; c < 12; ++c) if (ryb == c) ryres = v[61 + c];

  const float APC = 0.5235987755982988f;    // (f32)(2pi/12)
  const float APC2 = 0.2617993877991494f;   // (f32)(pi/12)
  const float TWO_PI_F = 6.283185307179586f;
  const float PI_F = 3.141592653589793f;
  float ry = ryb * APC + ryres * APC2;
  ry = fmodf(ry, TWO_PI_F);
  if (ry < 0.0f) ry += TWO_PI_F;            // floored mod, matches np/jnp %
  if (ry > PI_F) ry -= TWO_PI_F;

  float ah = anchor[0], aw = anchor[1], al = anchor[2];
  float H = v[73] * ah + ah;
  float W = v[74] * aw + aw;
  float L = v[75] * al + al;
  Y += H * 0.5f;                            // y += h/2

  float* pr = ws_pr + (size_t)(img * PRE_PAD + r) * 7;
  pr[0] = X; pr[1] = Y; pr[2] = Z; pr[3] = H; pr[4] = W; pr[5] = L; pr[6] = ry;

  int o = img * PRE_PAD + r;
  float x1 = X - L * 0.5f, x2 = X + L * 0.5f;
  float z1 = Z - W * 0.5f, z2 = Z + W * 0.5f;
  bev[o] = x1;
  bev[SZB + o] = x2;
  bev[2 * SZB + o] = z1;
  bev[3 * SZB + o] = z2;
  bev[4 * SZB + o] = (x2 - x1) * (z2 - z1);
}

// Kernel 3: all-pairs (i<j) IoU > 0.8 -> sparse edge list per image.
// Column box cached in registers; row reads are same-address LDS broadcasts.
__global__ __launch_bounds__(256) void k_pairs(
    const float* __restrict__ bev, uint32_t* __restrict__ edges,
    int* __restrict__ edge_cnt) {
  int bx = blockIdx.x;
  int img = bx / NTRI;
  int t = bx - img * NTRI;
  int ti = 0, acc = 0;
#pragma unroll
  for (int row = 0; row < TI; ++row) {
    int c = TI - row;
    if (t < acc + c) { ti = row; break; }
    acc += c;
  }
  int tj = ti + (t - acc);

  __shared__ float rx1[128], rx2[128], rz1[128], rz2[128], ra[128];
  __shared__ float cx1[128], cx2[128], cz1[128], cz2[128], ca[128];
  int tid = threadIdx.x;
  if (tid < 128) {
    int o = img * PRE_PAD + ti * 128 + tid;
    rx1[tid] = bev[o];           rx2[tid] = bev[SZB + o];
    rz1[tid] = bev[2 * SZB + o]; rz2[tid] = bev[3 * SZB + o];
    ra[tid] = bev[4 * SZB + o];
  } else {
    int q = tid - 128;
    int o = img * PRE_PAD + tj * 128 + q;
    cx1[q] = bev[o];             cx2[q] = bev[SZB + o];
    cz1[q] = bev[2 * SZB + o];   cz2[q] = bev[3 * SZB + o];
    ca[q] = bev[4 * SZB + o];
  }
  __syncthreads();

  const int b = tid & 127;
  const int a0 = tid >> 7;
  const float bx1 = cx1[b], bx2 = cx2[b], bz1 = cz1[b], bz2 = cz2[b],
              bar = ca[b];
  const int j = tj * 128 + b;
  for (int a = a0; a < 128; a += 2) {
    int i = ti * 128 + a;
    if (i < j && j < PRE) {
      float iw = fminf(rx2[a], bx2) - fmaxf(rx1[a], bx1);
      iw = fmaxf(iw, 0.0f);
      float ih = fminf(rz2[a], bz2) - fmaxf(rz1[a], bz1);
      ih = fmaxf(ih, 0.0f);
      float inter = iw * ih;
      float iou = inter / (ra[a] + bar - inter);  // true IEEE div, ref-exact
      if (iou > NMS_T) {
        int e = atomicAdd(&edge_cnt[img], 1);
        if (e < ECAP) edges[img * ECAP + e] = ((uint32_t)i << 16) | (uint32_t)j;
      }
    }
  }
}

// Kernel 4: resolve greedy NMS over sorted sparse edges, rank kept boxes,
// emit first POST kept boxes + scores (zero-fill the rest).
// v2: edge sort + serial walk done barrier-free by wave 0; keep-flag scan is
// wave-segmented (3 barriers instead of 12).
__global__ __launch_bounds__(1024) void k_resolve(
    const uint32_t* __restrict__ edges, const int* __restrict__ edge_cnt,
    const float* __restrict__ ws_pr, const float* __restrict__ ws_score,
    float* __restrict__ out) {
  __shared__ uint32_t sup[PRE];     // 9 KB
  __shared__ uint32_t earr[ECAP];   // 16 KB
  __shared__ uint32_t scn[SORTN];   // 16 KB
  __shared__ uint32_t addw[16];
  int img = blockIdx.x, tid = threadIdx.x;
  const int wave = tid >> 6, lane = tid & 63;

  for (int i = tid; i < PRE; i += 1024) sup[i] = 0u;
  int E = edge_cnt[img];
  if (E > ECAP) E = ECAP;
  if (E < 0) E = 0;
  int P2 = 1;
  while (P2 < E) P2 <<= 1;
  for (int e = tid; e < P2; e += 1024)
    earr[e] = (e < E) ? edges[img * ECAP + e] : 0xFFFFFFFFu;
  __syncthreads();

  // wave 0: bitonic sort of P2 edges + sequential greedy walk, barrier-free
  if (wave == 0) {
    volatile uint32_t* ve = earr;
    for (int k = 2; k <= P2; k <<= 1) {
      for (int j = k >> 1; j > 0; j >>= 1) {
        for (int t = lane; t < (P2 >> 1); t += 64) {
          int i = ((t & ~(j - 1)) << 1) | (t & (j - 1));
          int l = i | j;
          uint32_t a = ve[i], b = ve[l];
          if ((a > b) == ((i & k) == 0)) { ve[i] = b; ve[l] = a; }
        }
      }
    }
    if (lane == 0) {
      // edges sorted by source i asc => sup[i] final when visited
      volatile uint32_t* vsup = sup;
      for (int e = 0; e < E; ++e) {
        uint32_t u = ve[e];
        uint32_t i = u >> 16, j = u & 0xFFFFu;
        if (!vsup[i]) vsup[j] = 1u;
      }
    }
  }
  __syncthreads();

  // wave-segmented inclusive scan of keep flags -> ranks
  for (int q = tid; q < SORTN; q += 1024)
    scn[q] = (q < PRE && !sup[q]) ? 1u : 0u;
  __syncthreads();
  {
    volatile uint32_t* vsc = scn;
    const int b0 = wave * 256;
    for (int off = 1; off < 256; off <<= 1) {
      uint32_t nv[4];
#pragma unroll
      for (int r = 0; r < 4; ++r) {
        int t = lane + r * 64;
        uint32_t x = vsc[b0 + t];
        if (t >= off) x += vsc[b0 + t - off];
        nv[r] = x;
      }
#pragma unroll
      for (int r = 0; r < 4; ++r) vsc[b0 + lane + r * 64] = nv[r];
    }
  }
  __syncthreads();
  if (tid < 16) {  // addw[w] = total keeps in segments strictly left of w
    uint32_t s = 0;
    for (int w = 0; w < tid; ++w) s += scn[w * 256 + 255];
    addw[tid] = s;
  }
  __syncthreads();
  int total = (int)(addw[15] + scn[SORTN - 1]);

  float* ob = out + (size_t)img * POST * 7;
  float* os = out + (size_t)BN * POST * 7 + img * POST;
  for (int q = tid; q < PRE; q += 1024) {
    if (!sup[q]) {
      int rk = (int)(scn[q] + addw[q >> 8]) - 1;
      if (rk < POST) {
        const float* p = ws_pr + (size_t)(img * PRE_PAD + q) * 7;
#pragma unroll
        for (int c = 0; c < 7; ++c) ob[rk * 7 + c] = p[c];
        os[rk] = ws_score[img * PRE_PAD + q];
      }
    }
  }
  for (int rk = total + tid; rk < POST; rk += 1024) {
#pragma unroll
    for (int c = 0; c < 7; ++c) ob[rk * 7 + c] = 0.0f;
    os[rk] = 0.0f;
  }
}

extern "C" void kernel_launch(void* const* d_in, const int* in_sizes, int n_in,
                              void* d_out, int out_size, void* d_ws, size_t ws_size,
                              hipStream_t stream) {
  const float* scores = (const float*)d_in[0];
  const float* reg = (const float*)d_in[1];
  const float* xyz = (const float*)d_in[2];
  const float* anchor = (const float*)d_in[3];
  float* out = (float*)d_out;
  char* ws = (char*)d_ws;

  // workspace layout (bytes)
  int* ws_idx = (int*)(ws + 0);                 // BN*PRE_PAD int     = 36864
  float* ws_score = (float*)(ws + 36864);       // BN*PRE_PAD f32    += 36864
  float* ws_pr = (float*)(ws + 73728);          // BN*PRE_PAD*7 f32  += 258048
  float* bev = (float*)(ws + 331776);           // 5*BN*PRE_PAD f32  += 184320
  uint32_t* edges = (uint32_t*)(ws + 516096);   // BN*ECAP u32       += 65536
  int* edge_cnt = (int*)(ws + 581632);          // BN int

  k_select_sort<<<BN, 512, 0, stream>>>(scores, ws_idx, ws_score, edge_cnt);
  k_decode<<<(BN * PRE + 255) / 256, 256, 0, stream>>>(reg, xyz, anchor, ws_idx,
                                                       ws_pr, bev);
  k_pairs<<<BN * NTRI, 256, 0, stream>>>(bev, edges, edge_cnt);
  k_resolve<<<BN, 1024, 0, stream>>>(edges, edge_cnt, ws_pr, ws_score, out);
}

// Round 3
// 146.662 us; speedup vs baseline: 1.2742x; 1.2742x over previous
//
#include <hip/hip_runtime.h>
#include <stdint.h>

// ---- problem constants (PointRCNN RPN, KITTI Car) ----
#define BN 4
#define NPTS 16384
#define REGC 76
#define PRE 2250
#define PRE_PAD 2304          // 18*128, padded stride
#define POST 128
#define NBINS 4096            // 12-bit histogram on flipped float key
#define SORTN 4096            // candidate-set capacity
#define ECAP 4096             // max suppression edges per image
#define NMS_T 0.8f
#define TI 18                 // ceil(PRE/128)
#define NTRI 171              // TI*(TI+1)/2 upper-triangle tiles per image
#define SZB (BN * PRE_PAD)    // per-array stride for BEV SoA

// Order-preserving float->uint flip: ascending uint == ascending float.
__device__ __forceinline__ uint32_t flip_f32(float f) {
  uint32_t u = __float_as_uint(f);
  return (u & 0x80000000u) ? ~u : (u | 0x80000000u);
}
__device__ __forceinline__ float unflip_f32(uint32_t k) {
  uint32_t u = (k & 0x80000000u) ? (k & 0x7FFFFFFFu) : ~k;
  return __uint_as_float(u);
}

// Kernel 1: per image, histogram scores (12-bit bins of flipped key), find
// threshold bin bt (suffix count crosses PRE), compact all candidates with
// bin >= bt to global selkeys as u64 (~flipped<<32 | idx): ascending u64 ==
// (score desc, idx asc). No sort here — ranking kernel orders them.
__global__ __launch_bounds__(1024) void k_hist(
    const float* __restrict__ scores, unsigned long long* __restrict__ selkeys,
    int* __restrict__ sel_cnt, int* __restrict__ edge_cnt) {
  __shared__ uint32_t hist[NBINS];   // 16 KB
  __shared__ uint32_t wsum[16];
  __shared__ int s_bt, s_cnt;
  const int img = blockIdx.x, tid = threadIdx.x;
  const int wave = tid >> 6, lane = tid & 63;
  const float* sc = scores + img * NPTS;

  for (int i = tid; i < NBINS; i += 1024) hist[i] = 0u;
  if (tid == 0) { s_cnt = 0; edge_cnt[img] = 0; }
  __syncthreads();

  uint32_t k0[16];
#pragma unroll
  for (int r = 0; r < 16; ++r) {
    k0[r] = flip_f32(sc[tid + r * 1024]);
    atomicAdd(&hist[k0[r] >> 20], 1u);
  }
  __syncthreads();

  // suffix counts: thread owns 4 contiguous bins [4t, 4t+3]
  uint32_t b0 = hist[4 * tid + 0], b1 = hist[4 * tid + 1];
  uint32_t b2 = hist[4 * tid + 2], b3 = hist[4 * tid + 3];
  uint32_t s3 = b3, s2 = b2 + s3, s1 = b1 + s2, s0 = b0 + s1;
  const uint32_t tot = s0;
  uint32_t run = tot;  // inclusive suffix scan across wave (right-to-left)
#pragma unroll
  for (int off = 1; off < 64; off <<= 1) {
    uint32_t v = __shfl_down(run, off);
    if (lane + off < 64) run += v;
  }
  if (lane == 0) wsum[wave] = run;
  __syncthreads();
  uint32_t tail = 0;
  for (int w = wave + 1; w < 16; ++w) tail += wsum[w];
  const uint32_t after = run - tot + tail;  // suffix strictly after my bins
  const uint32_t S0 = s0 + after, S1 = s1 + after, S2 = s2 + after,
                 S3 = s3 + after;
  const uint32_t P = PRE;
  if (S0 >= P && S1 < P) s_bt = 4 * tid + 0;
  if (S1 >= P && S2 < P) s_bt = 4 * tid + 1;
  if (S2 >= P && S3 < P) s_bt = 4 * tid + 2;
  if (S3 >= P && after < P) s_bt = 4 * tid + 3;
  __syncthreads();
  const int bt = s_bt;

#pragma unroll
  for (int r = 0; r < 16; ++r) {
    if ((int)(k0[r] >> 20) >= bt) {
      int p = atomicAdd(&s_cnt, 1);
      if (p < SORTN)
        selkeys[img * SORTN + p] =
            ((unsigned long long)(~k0[r]) << 32) | (uint32_t)(tid + r * 1024);
    }
  }
  __syncthreads();
  if (tid == 0) sel_cnt[img] = s_cnt < SORTN ? s_cnt : SORTN;
}

// Kernel 2: rank each candidate (rank = #{keys < mine}; exact & stable since
// keys are unique), then FUSED decode: the thread that owns sorted slot r
// decodes its box and writes ws_score/ws_pr/bev at r directly.
__global__ __launch_bounds__(512) void k_rankdec(
    const unsigned long long* __restrict__ selkeys,
    const int* __restrict__ sel_cnt, const float* __restrict__ reg,
    const float* __restrict__ xyz, const float* __restrict__ anchor,
    float* __restrict__ ws_score, float* __restrict__ ws_pr,
    float* __restrict__ bev) {
  const int img = blockIdx.x >> 3;
  const int chunk = blockIdx.x & 7;
  const int tid = threadIdx.x;
  const int cnt = sel_cnt[img];
  if (chunk * 512 >= cnt) return;  // block-uniform exit, before any barrier
  __shared__ unsigned long long tile[512];
  const int i = chunk * 512 + tid;
  const unsigned long long myk = (i < cnt) ? selkeys[img * SORTN + i] : ~0ULL;
  int rank = 0;
  for (int t0 = 0; t0 < cnt; t0 += 512) {
    __syncthreads();
    const int m = min(512, cnt - t0);
    if (tid < m) tile[tid] = selkeys[img * SORTN + t0 + tid];
    __syncthreads();
    int q = 0;
    for (; q + 8 <= m; q += 8) {  // wave-uniform LDS addrs -> broadcast reads
      rank += (int)(tile[q + 0] < myk) + (int)(tile[q + 1] < myk) +
              (int)(tile[q + 2] < myk) + (int)(tile[q + 3] < myk) +
              (int)(tile[q + 4] < myk) + (int)(tile[q + 5] < myk) +
              (int)(tile[q + 6] < myk) + (int)(tile[q + 7] < myk);
    }
    for (; q < m; ++q) rank += (int)(tile[q] < myk);
  }
  if (i >= cnt || rank >= PRE) return;

  const int r = rank;
  const int idx = (int)(uint32_t)myk;
  ws_score[img * PRE_PAD + r] = unflip_f32(~(uint32_t)(myk >> 32));

  const float* rr = reg + (size_t)(img * NPTS + idx) * REGC;
  float v[REGC];
  const float4* r4 = reinterpret_cast<const float4*>(rr);
#pragma unroll
  for (int q = 0; q < REGC / 4; ++q) {
    float4 f = r4[q];
    v[4 * q + 0] = f.x; v[4 * q + 1] = f.y;
    v[4 * q + 2] = f.z; v[4 * q + 3] = f.w;
  }

  // first-occurrence argmax (strict >) matches jnp.argmax
  int xb = 0; float xm = v[0];
#pragma unroll
  for (int c = 1; c < 12; ++c) if (v[c] > xm) { xm = v[c]; xb = c; }
  int zb = 0; float zm = v[12];
#pragma unroll
  for (int c = 1; c < 12; ++c) if (v[12 + c] > zm) { zm = v[12 + c]; zb = c; }
  float xres = v[24];
#pragma unroll
  for (int c = 1; c < 12; ++c) if (xb == c) xres = v[24 + c];
  float zres = v[36];
#pragma unroll
  for (int c = 1; c < 12; ++c) if (zb == c) zres = v[36 + c];

  float posx = xb * 0.5f + 0.25f - 3.0f + xres * 0.5f;
  float posz = zb * 0.5f + 0.25f - 3.0f + zres * 0.5f;

  const float* xp = xyz + (size_t)(img * NPTS + idx) * 3;
  float X = posx + xp[0];
  float Y = xp[1] + v[48];
  float Z = posz + xp[2];

  int ryb = 0; float rym = v[49];
#pragma unroll
  for (int c = 1; c < 12; ++c) if (v[49 + c] > rym) { rym = v[49 + c]; ryb = c; }
  float ryres = v[61];
#pragma unroll
  for (int c = 1; c < 12; ++c) if (ryb == c) ryres = v[61 + c];

  const float APC = 0.5235987755982988f;    // (f32)(2pi/12)
  const float APC2 = 0.2617993877991494f;   // (f32)(pi/12)
  const float TWO_PI_F = 6.283185307179586f;
  const float PI_F = 3.141592653589793f;
  float ry = ryb * APC + ryres * APC2;
  ry = fmodf(ry, TWO_PI_F);
  if (ry < 0.0f) ry += TWO_PI_F;            // floored mod, matches np/jnp %
  if (ry > PI_F) ry -= TWO_PI_F;

  float ah = anchor[0], aw = anchor[1], al = anchor[2];
  float H = v[73] * ah + ah;
  float W = v[74] * aw + aw;
  float L = v[75] * al + al;
  Y += H * 0.5f;                            // y += h/2

  float* pr = ws_pr + (size_t)(img * PRE_PAD + r) * 7;
  pr[0] = X; pr[1] = Y; pr[2] = Z; pr[3] = H; pr[4] = W; pr[5] = L; pr[6] = ry;

  int o = img * PRE_PAD + r;
  float x1 = X - L * 0.5f, x2 = X + L * 0.5f;
  float z1 = Z - W * 0.5f, z2 = Z + W * 0.5f;
  bev[o] = x1;
  bev[SZB + o] = x2;
  bev[2 * SZB + o] = z1;
  bev[3 * SZB + o] = z2;
  bev[4 * SZB + o] = (x2 - x1) * (z2 - z1);
}

// Kernel 3: all-pairs (i<j) IoU > 0.8 -> sparse edge list per image.
// Column box cached in registers; row reads are same-address LDS broadcasts.
__global__ __launch_bounds__(256) void k_pairs(
    const float* __restrict__ bev, uint32_t* __restrict__ edges,
    int* __restrict__ edge_cnt) {
  int bx = blockIdx.x;
  int img = bx / NTRI;
  int t = bx - img * NTRI;
  int ti = 0, acc = 0;
#pragma unroll
  for (int row = 0; row < TI; ++row) {
    int c = TI - row;
    if (t < acc + c) { ti = row; break; }
    acc += c;
  }
  int tj = ti + (t - acc);

  __shared__ float rx1[128], rx2[128], rz1[128], rz2[128], ra[128];
  __shared__ float cx1[128], cx2[128], cz1[128], cz2[128], ca[128];
  int tid = threadIdx.x;
  if (tid < 128) {
    int o = img * PRE_PAD + ti * 128 + tid;
    rx1[tid] = bev[o];           rx2[tid] = bev[SZB + o];
    rz1[tid] = bev[2 * SZB + o]; rz2[tid] = bev[3 * SZB + o];
    ra[tid] = bev[4 * SZB + o];
  } else {
    int q = tid - 128;
    int o = img * PRE_PAD + tj * 128 + q;
    cx1[q] = bev[o];             cx2[q] = bev[SZB + o];
    cz1[q] = bev[2 * SZB + o];   cz2[q] = bev[3 * SZB + o];
    ca[q] = bev[4 * SZB + o];
  }
  __syncthreads();

  const int b = tid & 127;
  const int a0 = tid >> 7;
  const float bx1 = cx1[b], bx2 = cx2[b], bz1 = cz1[b], bz2 = cz2[b],
              bar = ca[b];
  const int j = tj * 128 + b;
  for (int a = a0; a < 128; a += 2) {
    int i = ti * 128 + a;
    if (i < j && j < PRE) {
      float iw = fminf(rx2[a], bx2) - fmaxf(rx1[a], bx1);
      iw = fmaxf(iw, 0.0f);
      float ih = fminf(rz2[a], bz2) - fmaxf(rz1[a], bz1);
      ih = fmaxf(ih, 0.0f);
      float inter = iw * ih;
      float iou = inter / (ra[a] + bar - inter);  // true IEEE div, ref-exact
      if (iou > NMS_T) {
        int e = atomicAdd(&edge_cnt[img], 1);
        if (e < ECAP) edges[img * ECAP + e] = ((uint32_t)i << 16) | (uint32_t)j;
      }
    }
  }
}

// Kernel 4: greedy-NMS resolve on sorted sparse edges; keep-flag ranks via
// shfl wave-scan (3 barriers); emit first POST kept boxes+scores, zero-fill.
__global__ __launch_bounds__(1024) void k_resolve(
    const uint32_t* __restrict__ edges, const int* __restrict__ edge_cnt,
    const float* __restrict__ ws_pr, const float* __restrict__ ws_score,
    float* __restrict__ out) {
  __shared__ uint32_t sup[PRE];     // 9 KB
  __shared__ uint32_t earr[ECAP];   // 16 KB
  __shared__ uint32_t wtot[16];
  const int img = blockIdx.x, tid = threadIdx.x;
  const int wave = tid >> 6, lane = tid & 63;

  for (int i = tid; i < PRE; i += 1024) sup[i] = 0u;
  int E = edge_cnt[img];
  E = E < 0 ? 0 : (E > ECAP ? ECAP : E);
  int P2 = 1;
  while (P2 < E) P2 <<= 1;
  for (int e = tid; e < P2; e += 1024)
    earr[e] = (e < E) ? edges[img * ECAP + e] : 0xFFFFFFFFu;
  __syncthreads();

  // wave 0: sort edges asc by (i<<16|j), then sequential greedy walk.
  if (wave == 0) {
    volatile uint32_t* ve = earr;
    for (int k = 2; k <= P2; k <<= 1)
      for (int j = k >> 1; j > 0; j >>= 1)
        for (int t = lane; t < (P2 >> 1); t += 64) {
          int ii = ((t & ~(j - 1)) << 1) | (t & (j - 1));
          int l = ii | j;
          uint32_t a = ve[ii], b = ve[l];
          if ((a > b) == ((ii & k) == 0)) { ve[ii] = b; ve[l] = a; }
        }
    if (lane == 0) {
      volatile uint32_t* vsup = sup;
      for (int e = 0; e < E; ++e) {
        uint32_t u = ve[e];
        uint32_t si = u >> 16, sj = u & 0xFFFFu;
        if (!vsup[si]) vsup[sj] = 1u;  // source-sorted => sup[si] final here
      }
    }
  }
  __syncthreads();

  // ranks: 4 contiguous elements/thread, shfl inclusive scan across wave
  const int q0 = 4 * tid;
  uint32_t f0 = (q0 + 0 < PRE && !sup[q0 + 0]) ? 1u : 0u;
  uint32_t f1 = (q0 + 1 < PRE && !sup[q0 + 1]) ? 1u : 0u;
  uint32_t f2 = (q0 + 2 < PRE && !sup[q0 + 2]) ? 1u : 0u;
  uint32_t f3 = (q0 + 3 < PRE && !sup[q0 + 3]) ? 1u : 0u;
  uint32_t p0 = f0, p1 = p0 + f1, p2 = p1 + f2, p3 = p2 + f3;
  const uint32_t tot = p3;
  uint32_t run = tot;
#pragma unroll
  for (int off = 1; off < 64; off <<= 1) {
    uint32_t v = __shfl_up(run, off);
    if (lane >= off) run += v;
  }
  if (lane == 63) wtot[wave] = run;
  __syncthreads();
  uint32_t wbase = 0, total = 0;
  for (int w = 0; w < 16; ++w) {
    uint32_t t = wtot[w];
    if (w < wave) wbase += t;
    total += t;
  }
  const uint32_t before = wbase + run - tot;  // exclusive prefix at q0

  float* ob = out + (size_t)img * POST * 7;
  float* os = out + (size_t)(BN * POST * 7) + img * POST;
  uint32_t fc[4] = {f0, f1, f2, f3};
  uint32_t pc[4] = {p0, p1, p2, p3};
#pragma unroll
  for (int c = 0; c < 4; ++c) {
    if (fc[c]) {
      int rk = (int)(before + pc[c]) - 1;
      if (rk < POST) {
        const float* p = ws_pr + (size_t)(img * PRE_PAD + (q0 + c)) * 7;
#pragma unroll
        for (int cc = 0; cc < 7; ++cc) ob[rk * 7 + cc] = p[cc];
        os[rk] = ws_score[img * PRE_PAD + (q0 + c)];
      }
    }
  }
  for (int rk = (int)total + tid; rk < POST; rk += 1024) {
#pragma unroll
    for (int cc = 0; cc < 7; ++cc) ob[rk * 7 + cc] = 0.0f;
    os[rk] = 0.0f;
  }
}

extern "C" void kernel_launch(void* const* d_in, const int* in_sizes, int n_in,
                              void* d_out, int out_size, void* d_ws, size_t ws_size,
                              hipStream_t stream) {
  const float* scores = (const float*)d_in[0];
  const float* reg = (const float*)d_in[1];
  const float* xyz = (const float*)d_in[2];
  const float* anchor = (const float*)d_in[3];
  float* out = (float*)d_out;
  char* ws = (char*)d_ws;

  // workspace layout (bytes); selkeys region is reused for edges afterwards
  // (selkeys dead after k_rankdec; k_pairs runs later on the same stream)
  unsigned long long* selkeys = (unsigned long long*)(ws + 0);  // 131072
  uint32_t* edges = (uint32_t*)(ws + 0);                        // 65536 (alias)
  float* ws_score = (float*)(ws + 131072);      // BN*PRE_PAD f32    = 36864
  float* ws_pr = (float*)(ws + 167936);         // BN*PRE_PAD*7 f32  = 258048
  float* bev = (float*)(ws + 425984);           // 5*SZB f32         = 184320
  int* sel_cnt = (int*)(ws + 610304);           // BN int
  int* edge_cnt = (int*)(ws + 610320);          // BN int

  k_hist<<<BN, 1024, 0, stream>>>(scores, selkeys, sel_cnt, edge_cnt);
  k_rankdec<<<BN * 8, 512, 0, stream>>>(selkeys, sel_cnt, reg, xyz, anchor,
                                        ws_score, ws_pr, bev);
  k_pairs<<<BN * NTRI, 256, 0, stream>>>(bev, edges, edge_cnt);
  k_resolve<<<BN, 1024, 0, stream>>>(edges, edge_cnt, ws_pr, ws_score, out);
}